// Round 1
// baseline (2275.406 us; speedup 1.0000x reference)
//
#include <hip/hip_runtime.h>
#include <hip/hip_bf16.h>
#include <math.h>

#define N_NODES 40000
#define N_EDGES 1280000
#define D_FEAT 1024
#define HIDDEN 64
#define N_CLASSES 40

// ---------------- degree / dinv ----------------

__global__ void k_init_deg(int* __restrict__ deg) {
    int i = blockIdx.x * blockDim.x + threadIdx.x;
    if (i < N_NODES) deg[i] = 1;  // self-loop
}

__global__ void k_count_deg(const int* __restrict__ col, int* __restrict__ deg) {
    int i = blockIdx.x * blockDim.x + threadIdx.x;
    if (i < N_EDGES) atomicAdd(&deg[col[i]], 1);
}

__global__ void k_dinv(const int* __restrict__ deg, float* __restrict__ dinv) {
    int i = blockIdx.x * blockDim.x + threadIdx.x;
    if (i < N_NODES) dinv[i] = rsqrtf((float)deg[i]);
}

// ---------------- GEMM1: hs1[i,j] = (x[i,:] @ W1[:,j]) * dinv[i] ----------------
// 64x64 tile, BK=16, 256 threads, 4x4 microtile per thread.

__global__ __launch_bounds__(256) void k_gemm1(const float* __restrict__ X,
                                               const float* __restrict__ W,
                                               const float* __restrict__ dinv,
                                               float* __restrict__ out) {
    __shared__ float As[64][17];  // +1 pad breaks store conflicts
    __shared__ float Bs[16][64];
    const int tid = threadIdx.x;
    const int tx = tid & 15, ty = tid >> 4;
    const int row0 = blockIdx.x * 64;

    const int lr = tid >> 2;         // 0..63 : A row to load
    const int lk = (tid & 3) * 4;    // k offset for A load (float4)
    const int bk = tid >> 4;         // 0..15 : B k-row to load
    const int bc = (tid & 15) * 4;   // B col (float4)

    float acc[4][4] = {};

    for (int k0 = 0; k0 < D_FEAT; k0 += 16) {
        float4 av = *(const float4*)&X[(row0 + lr) * D_FEAT + k0 + lk];
        As[lr][lk + 0] = av.x; As[lr][lk + 1] = av.y;
        As[lr][lk + 2] = av.z; As[lr][lk + 3] = av.w;
        float4 bv = *(const float4*)&W[(k0 + bk) * HIDDEN + bc];
        *(float4*)&Bs[bk][bc] = bv;
        __syncthreads();
#pragma unroll
        for (int k = 0; k < 16; ++k) {
            float4 b4 = *(float4*)&Bs[k][tx * 4];
            float a0 = As[ty * 4 + 0][k];
            float a1 = As[ty * 4 + 1][k];
            float a2 = As[ty * 4 + 2][k];
            float a3 = As[ty * 4 + 3][k];
            acc[0][0] += a0 * b4.x; acc[0][1] += a0 * b4.y; acc[0][2] += a0 * b4.z; acc[0][3] += a0 * b4.w;
            acc[1][0] += a1 * b4.x; acc[1][1] += a1 * b4.y; acc[1][2] += a1 * b4.z; acc[1][3] += a1 * b4.w;
            acc[2][0] += a2 * b4.x; acc[2][1] += a2 * b4.y; acc[2][2] += a2 * b4.z; acc[2][3] += a2 * b4.w;
            acc[3][0] += a3 * b4.x; acc[3][1] += a3 * b4.y; acc[3][2] += a3 * b4.z; acc[3][3] += a3 * b4.w;
        }
        __syncthreads();
    }

#pragma unroll
    for (int i = 0; i < 4; ++i) {
        int r = row0 + ty * 4 + i;
        float dv = dinv[r];
        float4 o = make_float4(acc[i][0] * dv, acc[i][1] * dv, acc[i][2] * dv, acc[i][3] * dv);
        *(float4*)&out[r * HIDDEN + tx * 4] = o;
    }
}

// ---------------- scatter layer 1: acc[col] += hs[row], 64 feats ----------------

__global__ __launch_bounds__(256) void k_scatter1(const int* __restrict__ row,
                                                  const int* __restrict__ col,
                                                  const float* __restrict__ hs,
                                                  float* __restrict__ acc) {
    int idx = blockIdx.x * 256 + threadIdx.x;   // E*16 threads total
    int e = idx >> 4;
    int g = (idx & 15) * 4;
    if (e >= N_EDGES) return;
    int r = row[e], c = col[e];
    float4 v = *(const float4*)&hs[r * HIDDEN + g];
    float* dst = &acc[c * HIDDEN + g];
    atomicAdd(dst + 0, v.x);
    atomicAdd(dst + 1, v.y);
    atomicAdd(dst + 2, v.z);
    atomicAdd(dst + 3, v.w);
}

// ---------------- epilogue 1: a1 = relu(dinv*(acc+hs) + b1) (in place over acc) ----------------

__global__ void k_finish1(const float* __restrict__ acc, const float* __restrict__ hs,
                          const float* __restrict__ dinv, const float* __restrict__ b,
                          float* __restrict__ out) {
    int idx = blockIdx.x * 256 + threadIdx.x;
    if (idx >= N_NODES * HIDDEN) return;
    int node = idx >> 6, j = idx & 63;
    float v = dinv[node] * (acc[idx] + hs[idx]) + __ldg(&b[j]);
    out[idx] = v > 0.0f ? v : 0.0f;
}

// ---------------- GEMM2: hs2[n,c] = (a1[n,:] @ W2[:,c]) * dinv[n] ----------------
// 32 nodes per block of 256 threads; W2 (64x40) and A tile staged in LDS.

__global__ __launch_bounds__(256) void k_gemm2(const float* __restrict__ A,
                                               const float* __restrict__ W,
                                               const float* __restrict__ dinv,
                                               float* __restrict__ out) {
    __shared__ float Ws[HIDDEN * N_CLASSES];  // 2560
    __shared__ float Aa[32][65];
    const int tid = threadIdx.x;
    const int node0 = blockIdx.x * 32;

    for (int i = tid; i < HIDDEN * N_CLASSES; i += 256) Ws[i] = W[i];
    for (int i = tid * 4; i < 32 * HIDDEN; i += 1024) {
        float4 v = *(const float4*)&A[node0 * HIDDEN + i];
        int n = i >> 6, k = i & 63;
        Aa[n][k + 0] = v.x; Aa[n][k + 1] = v.y; Aa[n][k + 2] = v.z; Aa[n][k + 3] = v.w;
    }
    __syncthreads();

    const int n = tid >> 3;            // 0..31
    const int c0 = (tid & 7) * 5;      // 0..35, 5 classes each
    float acc[5] = {};
#pragma unroll
    for (int k = 0; k < HIDDEN; ++k) {
        float av = Aa[n][k];
#pragma unroll
        for (int j = 0; j < 5; ++j) acc[j] += av * Ws[k * N_CLASSES + c0 + j];
    }
    float dv = dinv[node0 + n];
#pragma unroll
    for (int j = 0; j < 5; ++j) out[(node0 + n) * N_CLASSES + c0 + j] = acc[j] * dv;
}

// ---------------- scatter layer 2: 40 feats ----------------

__global__ __launch_bounds__(256) void k_scatter2(const int* __restrict__ row,
                                                  const int* __restrict__ col,
                                                  const float* __restrict__ hs,
                                                  float* __restrict__ acc) {
    int idx = blockIdx.x * 256 + threadIdx.x;   // E*10 threads total
    int e = idx / 10;
    int g = (idx % 10) * 4;
    if (e >= N_EDGES) return;
    int r = row[e], c = col[e];
    float4 v = *(const float4*)&hs[r * N_CLASSES + g];
    float* dst = &acc[c * N_CLASSES + g];
    atomicAdd(dst + 0, v.x);
    atomicAdd(dst + 1, v.y);
    atomicAdd(dst + 2, v.z);
    atomicAdd(dst + 3, v.w);
}

// ---------------- epilogue 2 + log-softmax ----------------
// 64 nodes per block; staged through LDS for coalesced global IO.

__global__ __launch_bounds__(256) void k_finish2_lsm(const float* __restrict__ acc,
                                                     const float* __restrict__ hs,
                                                     const float* __restrict__ dinv,
                                                     const float* __restrict__ b,
                                                     float* __restrict__ out) {
    __shared__ float zs[64][41];
    __shared__ float lse[64];
    const int tid = threadIdx.x;
    const int node0 = blockIdx.x * 64;

    for (int i = tid; i < 64 * N_CLASSES; i += 256) {
        int n = i / N_CLASSES, c = i % N_CLASSES;
        int gi = node0 * N_CLASSES + i;
        zs[n][c] = dinv[node0 + n] * (acc[gi] + hs[gi]) + __ldg(&b[c]);
    }
    __syncthreads();
    if (tid < 64) {
        float m = -1e30f;
#pragma unroll
        for (int c = 0; c < N_CLASSES; ++c) m = fmaxf(m, zs[tid][c]);
        float s = 0.0f;
#pragma unroll
        for (int c = 0; c < N_CLASSES; ++c) s += expf(zs[tid][c] - m);
        lse[tid] = m + logf(s);
    }
    __syncthreads();
    for (int i = tid; i < 64 * N_CLASSES; i += 256) {
        int n = i / N_CLASSES, c = i % N_CLASSES;
        out[node0 * N_CLASSES + i] = zs[n][c] - lse[n];
    }
}

// ---------------- launch ----------------

extern "C" void kernel_launch(void* const* d_in, const int* in_sizes, int n_in,
                              void* d_out, int out_size, void* d_ws, size_t ws_size,
                              hipStream_t stream) {
    const float* x  = (const float*)d_in[0];
    const int*   ei = (const int*)d_in[1];
    const float* W1 = (const float*)d_in[2];
    const float* b1 = (const float*)d_in[3];
    const float* W2 = (const float*)d_in[4];
    const float* b2 = (const float*)d_in[5];
    const int* row = ei;             // edge_index[0] = source
    const int* col = ei + N_EDGES;   // edge_index[1] = target

    char* ws = (char*)d_ws;
    int*   deg  = (int*)ws;                                    // 160 KB
    float* dinv = (float*)(ws + 160000);                       // 160 KB
    float* B1   = (float*)(ws + 320000);                       // 10.24 MB : hs1, later acc2
    float* B2   = (float*)(ws + 320000 + 10240000);            // 10.24 MB : acc1, later a1
    float* B3   = (float*)(ws + 320000 + 20480000);            // 6.4  MB : hs2

    hipMemsetAsync(B2, 0, N_NODES * HIDDEN * sizeof(float), stream);  // acc1 = 0
    k_init_deg<<<(N_NODES + 255) / 256, 256, 0, stream>>>(deg);
    k_count_deg<<<N_EDGES / 256, 256, 0, stream>>>(col, deg);
    k_dinv<<<(N_NODES + 255) / 256, 256, 0, stream>>>(deg, dinv);

    k_gemm1<<<N_NODES / 64, 256, 0, stream>>>(x, W1, dinv, B1);
    k_scatter1<<<(N_EDGES * 16) / 256, 256, 0, stream>>>(row, col, B1, B2);
    k_finish1<<<(N_NODES * HIDDEN) / 256, 256, 0, stream>>>(B2, B1, dinv, b1, B2);

    k_gemm2<<<N_NODES / 32, 256, 0, stream>>>(B2, W2, dinv, B3);
    hipMemsetAsync(B1, 0, N_NODES * N_CLASSES * sizeof(float), stream);  // acc2 = 0
    k_scatter2<<<(N_EDGES * 10) / 256, 256, 0, stream>>>(row, col, B3, B1);
    k_finish2_lsm<<<N_NODES / 64, 256, 0, stream>>>(B1, B3, dinv, b2, (float*)d_out);
}

// Round 2
// 559.729 us; speedup vs baseline: 4.0652x; 4.0652x over previous
//
#include <hip/hip_runtime.h>
#include <hip/hip_bf16.h>
#include <math.h>

#define N_NODES 40000
#define N_EDGES 1280000
#define D_FEAT 1024
#define HIDDEN 64
#define N_CLASSES 40
#define NBLK_SCAN ((N_NODES + 255) / 256)   // 157

// ---------------- degree count (incoming edges, no self-loop) ----------------

__global__ void k_count(const int* __restrict__ col, int* __restrict__ ecnt) {
    int i = blockIdx.x * blockDim.x + threadIdx.x;
    if (i < N_EDGES) atomicAdd(&ecnt[col[i]], 1);
}

__global__ void k_dinv(const int* __restrict__ ecnt, float* __restrict__ dinv) {
    int i = blockIdx.x * blockDim.x + threadIdx.x;
    if (i < N_NODES) dinv[i] = rsqrtf((float)(ecnt[i] + 1));  // +1 self-loop
}

// ---------------- 3-kernel exclusive scan over ecnt -> off/cursor ----------------

__global__ void k_scan1(const int* __restrict__ ecnt, int* __restrict__ partial,
                        int* __restrict__ bsum) {
    __shared__ int s[256];
    int i = blockIdx.x * 256 + threadIdx.x;
    s[threadIdx.x] = (i < N_NODES) ? ecnt[i] : 0;
    __syncthreads();
#pragma unroll
    for (int d = 1; d < 256; d <<= 1) {
        int t = (threadIdx.x >= d) ? s[threadIdx.x - d] : 0;
        __syncthreads();
        s[threadIdx.x] += t;
        __syncthreads();
    }
    if (i < N_NODES) partial[i] = s[threadIdx.x];          // inclusive within block
    if (threadIdx.x == 255) bsum[blockIdx.x] = s[255];
}

__global__ void k_scan2(int* __restrict__ bsum) {
    __shared__ int s[256];
    int i = threadIdx.x;
    s[i] = (i < NBLK_SCAN) ? bsum[i] : 0;
    __syncthreads();
#pragma unroll
    for (int d = 1; d < 256; d <<= 1) {
        int t = (i >= d) ? s[i - d] : 0;
        __syncthreads();
        s[i] += t;
        __syncthreads();
    }
    if (i < NBLK_SCAN) bsum[i] = s[i];                      // inclusive
}

__global__ void k_scan3(const int* __restrict__ ecnt, const int* __restrict__ partial,
                        const int* __restrict__ bsum, int* __restrict__ off,
                        int* __restrict__ cursor) {
    int i = blockIdx.x * 256 + threadIdx.x;
    if (i < N_NODES) {
        int excl = partial[i] - ecnt[i] + (blockIdx.x ? bsum[blockIdx.x - 1] : 0);
        off[i] = excl;
        cursor[i] = excl;
        if (i == N_NODES - 1) off[N_NODES] = excl + ecnt[i];
    }
}

// ---------------- positioning pass: sorted[pos] = row[e], bucketed by col ----------------

__global__ void k_position(const int* __restrict__ row, const int* __restrict__ col,
                           int* __restrict__ cursor, int* __restrict__ sorted) {
    int e = blockIdx.x * 256 + threadIdx.x;
    if (e < N_EDGES) {
        int p = atomicAdd(&cursor[col[e]], 1);
        sorted[p] = row[e];
    }
}

// ---------------- GEMM1: hs1[i,j] = (x[i,:] @ W1[:,j]) * dinv[i] ----------------

__global__ __launch_bounds__(256) void k_gemm1(const float* __restrict__ X,
                                               const float* __restrict__ W,
                                               const float* __restrict__ dinv,
                                               float* __restrict__ out) {
    __shared__ float As[64][17];
    __shared__ float Bs[16][64];
    const int tid = threadIdx.x;
    const int tx = tid & 15, ty = tid >> 4;
    const int row0 = blockIdx.x * 64;

    const int lr = tid >> 2;
    const int lk = (tid & 3) * 4;
    const int bk = tid >> 4;
    const int bc = (tid & 15) * 4;

    float acc[4][4] = {};

    for (int k0 = 0; k0 < D_FEAT; k0 += 16) {
        float4 av = *(const float4*)&X[(row0 + lr) * D_FEAT + k0 + lk];
        As[lr][lk + 0] = av.x; As[lr][lk + 1] = av.y;
        As[lr][lk + 2] = av.z; As[lr][lk + 3] = av.w;
        float4 bv = *(const float4*)&W[(k0 + bk) * HIDDEN + bc];
        *(float4*)&Bs[bk][bc] = bv;
        __syncthreads();
#pragma unroll
        for (int k = 0; k < 16; ++k) {
            float4 b4 = *(float4*)&Bs[k][tx * 4];
            float a0 = As[ty * 4 + 0][k];
            float a1 = As[ty * 4 + 1][k];
            float a2 = As[ty * 4 + 2][k];
            float a3 = As[ty * 4 + 3][k];
            acc[0][0] += a0 * b4.x; acc[0][1] += a0 * b4.y; acc[0][2] += a0 * b4.z; acc[0][3] += a0 * b4.w;
            acc[1][0] += a1 * b4.x; acc[1][1] += a1 * b4.y; acc[1][2] += a1 * b4.z; acc[1][3] += a1 * b4.w;
            acc[2][0] += a2 * b4.x; acc[2][1] += a2 * b4.y; acc[2][2] += a2 * b4.z; acc[2][3] += a2 * b4.w;
            acc[3][0] += a3 * b4.x; acc[3][1] += a3 * b4.y; acc[3][2] += a3 * b4.z; acc[3][3] += a3 * b4.w;
        }
        __syncthreads();
    }

#pragma unroll
    for (int i = 0; i < 4; ++i) {
        int r = row0 + ty * 4 + i;
        float dv = dinv[r];
        float4 o = make_float4(acc[i][0] * dv, acc[i][1] * dv, acc[i][2] * dv, acc[i][3] * dv);
        *(float4*)&out[r * HIDDEN + tx * 4] = o;
    }
}

// ---------------- gather 1: one wave per node, lane = feature; fused epilogue+ReLU ----------------

__global__ __launch_bounds__(256) void k_gather1(const int* __restrict__ off,
                                                 const int* __restrict__ sorted,
                                                 const float* __restrict__ hs,
                                                 const float* __restrict__ dinv,
                                                 const float* __restrict__ b,
                                                 float* __restrict__ out) {
    int node = (blockIdx.x * 256 + threadIdx.x) >> 6;
    int lane = threadIdx.x & 63;
    if (node >= N_NODES) return;
    int beg = off[node], end = off[node + 1];
    float acc = hs[node * HIDDEN + lane];          // self-loop term (hs = h*dinv)
    int j = beg;
    for (; j + 4 <= end; j += 4) {
        int s0 = sorted[j + 0], s1 = sorted[j + 1];
        int s2 = sorted[j + 2], s3 = sorted[j + 3];
        float v0 = hs[s0 * HIDDEN + lane];
        float v1 = hs[s1 * HIDDEN + lane];
        float v2 = hs[s2 * HIDDEN + lane];
        float v3 = hs[s3 * HIDDEN + lane];
        acc += v0; acc += v1; acc += v2; acc += v3;
    }
    for (; j < end; ++j) acc += hs[sorted[j] * HIDDEN + lane];
    float v = dinv[node] * acc + b[lane];
    out[node * HIDDEN + lane] = fmaxf(v, 0.0f);
}

// ---------------- GEMM2: hs2[n,c] = (a1[n,:] @ W2[:,c]) * dinv[n] ----------------

__global__ __launch_bounds__(256) void k_gemm2(const float* __restrict__ A,
                                               const float* __restrict__ W,
                                               const float* __restrict__ dinv,
                                               float* __restrict__ out) {
    __shared__ float Ws[HIDDEN * N_CLASSES];
    __shared__ float Aa[32][65];
    const int tid = threadIdx.x;
    const int node0 = blockIdx.x * 32;

    for (int i = tid; i < HIDDEN * N_CLASSES; i += 256) Ws[i] = W[i];
    for (int i = tid * 4; i < 32 * HIDDEN; i += 1024) {
        float4 v = *(const float4*)&A[node0 * HIDDEN + i];
        int n = i >> 6, k = i & 63;
        Aa[n][k + 0] = v.x; Aa[n][k + 1] = v.y; Aa[n][k + 2] = v.z; Aa[n][k + 3] = v.w;
    }
    __syncthreads();

    const int n = tid >> 3;
    const int c0 = (tid & 7) * 5;
    float acc[5] = {};
#pragma unroll
    for (int k = 0; k < HIDDEN; ++k) {
        float av = Aa[n][k];
#pragma unroll
        for (int j = 0; j < 5; ++j) acc[j] += av * Ws[k * N_CLASSES + c0 + j];
    }
    float dv = dinv[node0 + n];
#pragma unroll
    for (int j = 0; j < 5; ++j) out[(node0 + n) * N_CLASSES + c0 + j] = acc[j] * dv;
}

// ---------------- gather 2 + epilogue + log-softmax: one wave per node ----------------

__global__ __launch_bounds__(256) void k_gather2_lsm(const int* __restrict__ off,
                                                     const int* __restrict__ sorted,
                                                     const float* __restrict__ hs,
                                                     const float* __restrict__ dinv,
                                                     const float* __restrict__ b,
                                                     float* __restrict__ out) {
    int node = (blockIdx.x * 256 + threadIdx.x) >> 6;
    int lane = threadIdx.x & 63;
    if (node >= N_NODES) return;
    int beg = off[node], end = off[node + 1];
    bool act = lane < N_CLASSES;
    float acc = act ? hs[node * N_CLASSES + lane] : 0.0f;   // self-loop
    int j = beg;
    for (; j + 4 <= end; j += 4) {
        int s0 = sorted[j + 0], s1 = sorted[j + 1];
        int s2 = sorted[j + 2], s3 = sorted[j + 3];
        if (act) {
            acc += hs[s0 * N_CLASSES + lane];
            acc += hs[s1 * N_CLASSES + lane];
            acc += hs[s2 * N_CLASSES + lane];
            acc += hs[s3 * N_CLASSES + lane];
        }
    }
    for (; j < end; ++j) {
        int s = sorted[j];
        if (act) acc += hs[s * N_CLASSES + lane];
    }
    float z = act ? (dinv[node] * acc + b[lane]) : -INFINITY;
    float m = z;
#pragma unroll
    for (int d = 32; d > 0; d >>= 1) m = fmaxf(m, __shfl_xor(m, d, 64));
    float ex = act ? expf(z - m) : 0.0f;
    float s = ex;
#pragma unroll
    for (int d = 32; d > 0; d >>= 1) s += __shfl_xor(s, d, 64);
    float lse = m + logf(s);
    if (act) out[node * N_CLASSES + lane] = z - lse;
}

// ---------------- launch ----------------

extern "C" void kernel_launch(void* const* d_in, const int* in_sizes, int n_in,
                              void* d_out, int out_size, void* d_ws, size_t ws_size,
                              hipStream_t stream) {
    const float* x  = (const float*)d_in[0];
    const int*   ei = (const int*)d_in[1];
    const float* W1 = (const float*)d_in[2];
    const float* b1 = (const float*)d_in[3];
    const float* W2 = (const float*)d_in[4];
    const float* b2 = (const float*)d_in[5];
    const int* row = ei;             // edge_index[0] = source
    const int* col = ei + N_EDGES;   // edge_index[1] = target

    char* ws = (char*)d_ws;
    int*   ecnt    = (int*)(ws + 0);            // 160 KB
    float* dinv    = (float*)(ws + 163840);     // 160 KB
    int*   off     = (int*)(ws + 327680);       // 160 KB+4
    int*   cursor  = (int*)(ws + 491520);       // 160 KB
    int*   partial = (int*)(ws + 655360);       // 160 KB
    int*   bsum    = (int*)(ws + 819200);       // 1 KB
    int*   sorted  = (int*)(ws + 823296);       // 5.12 MB
    float* B1      = (float*)(ws + 5943296);    // 10.24 MB : hs1
    float* B2      = (float*)(ws + 16183296);   // 10.24 MB : a1
    float* B3      = (float*)(ws + 26423296);   // 6.4  MB : hs2

    hipMemsetAsync(ecnt, 0, N_NODES * sizeof(int), stream);
    k_count<<<N_EDGES / 256, 256, 0, stream>>>(col, ecnt);
    k_dinv<<<(N_NODES + 255) / 256, 256, 0, stream>>>(ecnt, dinv);

    k_scan1<<<NBLK_SCAN, 256, 0, stream>>>(ecnt, partial, bsum);
    k_scan2<<<1, 256, 0, stream>>>(bsum);
    k_scan3<<<NBLK_SCAN, 256, 0, stream>>>(ecnt, partial, bsum, off, cursor);
    k_position<<<N_EDGES / 256, 256, 0, stream>>>(row, col, cursor, sorted);

    k_gemm1<<<N_NODES / 64, 256, 0, stream>>>(x, W1, dinv, B1);
    k_gather1<<<(N_NODES + 3) / 4, 256, 0, stream>>>(off, sorted, B1, dinv, b1, B2);

    k_gemm2<<<N_NODES / 32, 256, 0, stream>>>(B2, W2, dinv, B3);
    k_gather2_lsm<<<(N_NODES + 3) / 4, 256, 0, stream>>>(off, sorted, B3, dinv, b2, (float*)d_out);
}

// Round 3
// 504.078 us; speedup vs baseline: 4.5140x; 1.1104x over previous
//
#include <hip/hip_runtime.h>
#include <hip/hip_bf16.h>
#include <math.h>

#define N_NODES 40000
#define N_EDGES 1280000
#define D_FEAT 1024
#define HIDDEN 64
#define N_CLASSES 40
#define NBLK_SCAN ((N_NODES + 255) / 256)   // 157

typedef _Float16 f16x8 __attribute__((ext_vector_type(8)));
typedef _Float16 f16x2 __attribute__((ext_vector_type(2)));
typedef float f32x4 __attribute__((ext_vector_type(4)));

// ---------------- degree count (incoming edges, no self-loop) ----------------

__global__ void k_count(const int* __restrict__ col, int* __restrict__ ecnt) {
    int i = blockIdx.x * blockDim.x + threadIdx.x;
    if (i < N_EDGES) atomicAdd(&ecnt[col[i]], 1);
}

__global__ void k_dinv(const int* __restrict__ ecnt, float* __restrict__ dinv) {
    int i = blockIdx.x * blockDim.x + threadIdx.x;
    if (i < N_NODES) dinv[i] = rsqrtf((float)(ecnt[i] + 1));  // +1 self-loop
}

// ---------------- W1 -> transposed f16 [HIDDEN][D_FEAT] ----------------

__global__ void k_convW1(const float* __restrict__ W, _Float16* __restrict__ Wt) {
    int i = blockIdx.x * 256 + threadIdx.x;
    if (i < D_FEAT * HIDDEN) {
        int n = i & 63, k = i >> 6;
        Wt[n * D_FEAT + k] = (_Float16)W[k * HIDDEN + n];
    }
}

// ---------------- 3-kernel exclusive scan over ecnt -> off/cursor ----------------

__global__ void k_scan1(const int* __restrict__ ecnt, int* __restrict__ partial,
                        int* __restrict__ bsum) {
    __shared__ int s[256];
    int i = blockIdx.x * 256 + threadIdx.x;
    s[threadIdx.x] = (i < N_NODES) ? ecnt[i] : 0;
    __syncthreads();
#pragma unroll
    for (int d = 1; d < 256; d <<= 1) {
        int t = (threadIdx.x >= d) ? s[threadIdx.x - d] : 0;
        __syncthreads();
        s[threadIdx.x] += t;
        __syncthreads();
    }
    if (i < N_NODES) partial[i] = s[threadIdx.x];
    if (threadIdx.x == 255) bsum[blockIdx.x] = s[255];
}

__global__ void k_scan2(int* __restrict__ bsum) {
    __shared__ int s[256];
    int i = threadIdx.x;
    s[i] = (i < NBLK_SCAN) ? bsum[i] : 0;
    __syncthreads();
#pragma unroll
    for (int d = 1; d < 256; d <<= 1) {
        int t = (i >= d) ? s[i - d] : 0;
        __syncthreads();
        s[i] += t;
        __syncthreads();
    }
    if (i < NBLK_SCAN) bsum[i] = s[i];
}

__global__ void k_scan3(const int* __restrict__ ecnt, const int* __restrict__ partial,
                        const int* __restrict__ bsum, int* __restrict__ off,
                        int* __restrict__ cursor) {
    int i = blockIdx.x * 256 + threadIdx.x;
    if (i < N_NODES) {
        int excl = partial[i] - ecnt[i] + (blockIdx.x ? bsum[blockIdx.x - 1] : 0);
        off[i] = excl;
        cursor[i] = excl;
        if (i == N_NODES - 1) off[N_NODES] = excl + ecnt[i];
    }
}

__global__ void k_position(const int* __restrict__ row, const int* __restrict__ col,
                           int* __restrict__ cursor, int* __restrict__ sorted) {
    int e = blockIdx.x * 256 + threadIdx.x;
    if (e < N_EDGES) {
        int p = atomicAdd(&cursor[col[e]], 1);
        sorted[p] = row[e];
    }
}

// ---------------- GEMM1 (f16 MFMA): hs1[i,j] = f16((x[i,:] @ W1[:,j]) * dinv[i]) ----------------
// 32x64 tile per 256-thread block (1250 blocks), BK=64, 4 waves of 16x32.

#define LDA 72   // 64 + 8 halves pad
#define LDB 72

__global__ __launch_bounds__(256) void k_gemm1(const float* __restrict__ X,
                                               const _Float16* __restrict__ Wt,
                                               const float* __restrict__ dinv,
                                               _Float16* __restrict__ out) {
    __shared__ _Float16 As[32 * LDA];
    __shared__ _Float16 Bs[64 * LDB];
    const int tid = threadIdx.x;
    const int wave = tid >> 6, lane = tid & 63;
    const int row0 = blockIdx.x * 32;
    const int m0 = (wave & 1) * 16, n0 = (wave >> 1) * 32;
    const int lr = lane & 15, quad = lane >> 4;

    const int ar = tid >> 3;          // 0..31 A row
    const int ak = (tid & 7) * 8;     // k offset (8 floats)
    const int bn = tid >> 2;          // 0..63 B row (n)
    const int bk = (tid & 3) * 16;    // k offset (16 halves)

    f32x4 acc0 = {0.f, 0.f, 0.f, 0.f};
    f32x4 acc1 = {0.f, 0.f, 0.f, 0.f};

    for (int k0 = 0; k0 < D_FEAT; k0 += 64) {
        const float* xp = &X[(row0 + ar) * D_FEAT + k0 + ak];
        float4 v0 = *(const float4*)xp;
        float4 v1 = *(const float4*)(xp + 4);
        _Float16* ad = &As[ar * LDA + ak];
        ad[0] = (_Float16)v0.x; ad[1] = (_Float16)v0.y;
        ad[2] = (_Float16)v0.z; ad[3] = (_Float16)v0.w;
        ad[4] = (_Float16)v1.x; ad[5] = (_Float16)v1.y;
        ad[6] = (_Float16)v1.z; ad[7] = (_Float16)v1.w;
        const uint4* wp = (const uint4*)&Wt[bn * D_FEAT + k0 + bk];
        uint4 w0 = wp[0], w1 = wp[1];
        *(uint4*)&Bs[bn * LDB + bk] = w0;
        *(uint4*)&Bs[bn * LDB + bk + 8] = w1;
        __syncthreads();
#pragma unroll
        for (int kk = 0; kk < 64; kk += 32) {
            f16x8 a  = *(f16x8*)&As[(m0 + lr) * LDA + kk + quad * 8];
            f16x8 b0 = *(f16x8*)&Bs[(n0 + lr) * LDB + kk + quad * 8];
            f16x8 b1 = *(f16x8*)&Bs[(n0 + 16 + lr) * LDB + kk + quad * 8];
            acc0 = __builtin_amdgcn_mfma_f32_16x16x32_f16(a, b0, acc0, 0, 0, 0);
            acc1 = __builtin_amdgcn_mfma_f32_16x16x32_f16(a, b1, acc1, 0, 0, 0);
        }
        __syncthreads();
    }

#pragma unroll
    for (int r = 0; r < 4; ++r) {
        int m = row0 + m0 + quad * 4 + r;
        float dv = dinv[m];
        out[m * HIDDEN + n0 + lr]      = (_Float16)(acc0[r] * dv);
        out[m * HIDDEN + n0 + 16 + lr] = (_Float16)(acc1[r] * dv);
    }
}

// ---------------- gather 1: one wave per node, 2 edges/iter via half2 lanes ----------------

__global__ __launch_bounds__(256) void k_gather1(const int* __restrict__ off,
                                                 const int* __restrict__ sorted,
                                                 const _Float16* __restrict__ hs,
                                                 const float* __restrict__ dinv,
                                                 const float* __restrict__ bias,
                                                 float* __restrict__ out) {
    int node = (blockIdx.x * 256 + threadIdx.x) >> 6;
    int lane = threadIdx.x & 63;
    if (node >= N_NODES) return;
    int h = lane >> 5, fl = lane & 31;
    float ax = 0.f, ay = 0.f;
    if (h == 0) {  // self-loop counted once
        f16x2 v = *(const f16x2*)&hs[node * HIDDEN + 2 * fl];
        ax = (float)v.x; ay = (float)v.y;
    }
    int beg = off[node], end = off[node + 1];
    int j = beg + h;
    for (; j + 2 < end; j += 4) {
        int s0 = sorted[j], s1 = sorted[j + 2];
        f16x2 v0 = *(const f16x2*)&hs[s0 * HIDDEN + 2 * fl];
        f16x2 v1 = *(const f16x2*)&hs[s1 * HIDDEN + 2 * fl];
        ax += (float)v0.x + (float)v1.x;
        ay += (float)v0.y + (float)v1.y;
    }
    for (; j < end; j += 2) {
        int s = sorted[j];
        f16x2 v = *(const f16x2*)&hs[s * HIDDEN + 2 * fl];
        ax += (float)v.x; ay += (float)v.y;
    }
    ax += __shfl_xor(ax, 32, 64);
    ay += __shfl_xor(ay, 32, 64);
    if (h == 0) {
        float dv = dinv[node];
        float2 o;
        o.x = fmaxf(fmaf(dv, ax, bias[2 * fl + 0]), 0.f);
        o.y = fmaxf(fmaf(dv, ay, bias[2 * fl + 1]), 0.f);
        *(float2*)&out[node * HIDDEN + 2 * fl] = o;
    }
}

// ---------------- GEMM2: hs2[n,c] = f16((a1[n,:] @ W2[:,c]) * dinv[n]) ----------------

__global__ __launch_bounds__(256) void k_gemm2(const float* __restrict__ A,
                                               const float* __restrict__ W,
                                               const float* __restrict__ dinv,
                                               _Float16* __restrict__ out) {
    __shared__ float Ws[HIDDEN * N_CLASSES];
    __shared__ float Aa[32][65];
    const int tid = threadIdx.x;
    const int node0 = blockIdx.x * 32;

    for (int i = tid; i < HIDDEN * N_CLASSES; i += 256) Ws[i] = W[i];
    for (int i = tid * 4; i < 32 * HIDDEN; i += 1024) {
        float4 v = *(const float4*)&A[node0 * HIDDEN + i];
        int n = i >> 6, k = i & 63;
        Aa[n][k + 0] = v.x; Aa[n][k + 1] = v.y; Aa[n][k + 2] = v.z; Aa[n][k + 3] = v.w;
    }
    __syncthreads();

    const int n = tid >> 3;
    const int c0 = (tid & 7) * 5;
    float acc[5] = {};
#pragma unroll
    for (int k = 0; k < HIDDEN; ++k) {
        float av = Aa[n][k];
#pragma unroll
        for (int j = 0; j < 5; ++j) acc[j] += av * Ws[k * N_CLASSES + c0 + j];
    }
    float dv = dinv[node0 + n];
#pragma unroll
    for (int j = 0; j < 5; ++j)
        out[(node0 + n) * N_CLASSES + c0 + j] = (_Float16)(acc[j] * dv);
}

// ---------------- gather 2 + epilogue + log-softmax: 2 edges/iter via half2 lanes ----------------

__global__ __launch_bounds__(256) void k_gather2_lsm(const int* __restrict__ off,
                                                     const int* __restrict__ sorted,
                                                     const _Float16* __restrict__ hs,
                                                     const float* __restrict__ dinv,
                                                     const float* __restrict__ bias,
                                                     float* __restrict__ out) {
    int node = (blockIdx.x * 256 + threadIdx.x) >> 6;
    int lane = threadIdx.x & 63;
    if (node >= N_NODES) return;
    int h = lane >> 5, fl = lane & 31;
    bool act = fl < 20;  // 20 half2 lanes cover 40 classes
    float ax = 0.f, ay = 0.f;
    if (h == 0 && act) {
        f16x2 v = *(const f16x2*)&hs[node * N_CLASSES + 2 * fl];
        ax = (float)v.x; ay = (float)v.y;
    }
    int beg = off[node], end = off[node + 1];
    int j = beg + h;
    for (; j + 2 < end; j += 4) {
        int s0 = sorted[j], s1 = sorted[j + 2];
        if (act) {
            f16x2 v0 = *(const f16x2*)&hs[s0 * N_CLASSES + 2 * fl];
            f16x2 v1 = *(const f16x2*)&hs[s1 * N_CLASSES + 2 * fl];
            ax += (float)v0.x + (float)v1.x;
            ay += (float)v0.y + (float)v1.y;
        }
    }
    for (; j < end; j += 2) {
        int s = sorted[j];
        if (act) {
            f16x2 v = *(const f16x2*)&hs[s * N_CLASSES + 2 * fl];
            ax += (float)v.x; ay += (float)v.y;
        }
    }
    ax += __shfl_xor(ax, 32, 64);
    ay += __shfl_xor(ay, 32, 64);
    float dv = dinv[node];
    float zx = act ? fmaf(dv, ax, bias[2 * fl + 0]) : -INFINITY;
    float zy = act ? fmaf(dv, ay, bias[2 * fl + 1]) : -INFINITY;
    float m = fmaxf(zx, zy);
#pragma unroll
    for (int d = 16; d > 0; d >>= 1) m = fmaxf(m, __shfl_xor(m, d, 64));
    float ex = act ? (expf(zx - m) + expf(zy - m)) : 0.f;
#pragma unroll
    for (int d = 16; d > 0; d >>= 1) ex += __shfl_xor(ex, d, 64);
    float lse = m + logf(ex);
    if (h == 0 && act) {
        float2 o; o.x = zx - lse; o.y = zy - lse;
        *(float2*)&out[node * N_CLASSES + 2 * fl] = o;
    }
}

// ---------------- launch ----------------

extern "C" void kernel_launch(void* const* d_in, const int* in_sizes, int n_in,
                              void* d_out, int out_size, void* d_ws, size_t ws_size,
                              hipStream_t stream) {
    const float* x  = (const float*)d_in[0];
    const int*   ei = (const int*)d_in[1];
    const float* W1 = (const float*)d_in[2];
    const float* b1 = (const float*)d_in[3];
    const float* W2 = (const float*)d_in[4];
    const float* b2 = (const float*)d_in[5];
    const int* row = ei;             // edge_index[0] = source
    const int* col = ei + N_EDGES;   // edge_index[1] = target

    char* ws = (char*)d_ws;
    int*      ecnt    = (int*)(ws + 0);             // 160 KB
    float*    dinv    = (float*)(ws + 163840);      // 160 KB
    int*      off     = (int*)(ws + 327680);        // 160 KB + 4
    int*      cursor  = (int*)(ws + 491520);        // 160 KB
    int*      partial = (int*)(ws + 655360);        // 160 KB
    int*      bsum    = (int*)(ws + 819200);        // 1 KB
    int*      sorted  = (int*)(ws + 823296);        // 5.12 MB
    _Float16* W1t     = (_Float16*)(ws + 5943296);  // 128 KB, f16 [64][1024]
    _Float16* B1      = (_Float16*)(ws + 6074368);  // 5.12 MB : hs1 f16
    float*    B2      = (float*)(ws + 11194368);    // 10.24 MB : a1 fp32
    _Float16* B3      = (_Float16*)(ws + 21434368); // 3.2 MB : hs2 f16

    hipMemsetAsync(ecnt, 0, N_NODES * sizeof(int), stream);
    k_count<<<N_EDGES / 256, 256, 0, stream>>>(col, ecnt);
    k_dinv<<<(N_NODES + 255) / 256, 256, 0, stream>>>(ecnt, dinv);
    k_convW1<<<(D_FEAT * HIDDEN) / 256, 256, 0, stream>>>(W1, W1t);

    k_scan1<<<NBLK_SCAN, 256, 0, stream>>>(ecnt, partial, bsum);
    k_scan2<<<1, 256, 0, stream>>>(bsum);
    k_scan3<<<NBLK_SCAN, 256, 0, stream>>>(ecnt, partial, bsum, off, cursor);
    k_position<<<N_EDGES / 256, 256, 0, stream>>>(row, col, cursor, sorted);

    k_gemm1<<<N_NODES / 32, 256, 0, stream>>>(x, W1t, dinv, B1);
    k_gather1<<<(N_NODES + 3) / 4, 256, 0, stream>>>(off, sorted, B1, dinv, b1, B2);

    k_gemm2<<<N_NODES / 32, 256, 0, stream>>>(B2, W2, dinv, B3);
    k_gather2_lsm<<<(N_NODES + 3) / 4, 256, 0, stream>>>(off, sorted, B3, dinv, b2, (float*)d_out);
}

// Round 4
// 427.321 us; speedup vs baseline: 5.3248x; 1.1796x over previous
//
#include <hip/hip_runtime.h>
#include <hip/hip_bf16.h>
#include <math.h>

#define N_NODES 40000
#define N_EDGES 1280000
#define D_FEAT 1024
#define HIDDEN 64
#define N_CLASSES 40
#define NB 157            // buckets of 256 destination cols: ceil(40000/256)
#define CHUNK 8192        // edges per k_binscatter block

typedef _Float16 f16x8 __attribute__((ext_vector_type(8)));
typedef _Float16 f16x2 __attribute__((ext_vector_type(2)));
typedef float f32x4 __attribute__((ext_vector_type(4)));

// ---------------- pass 0: bucket histogram (LDS-aggregated) ----------------

__global__ __launch_bounds__(256) void k_binhist(const int* __restrict__ col,
                                                 int* __restrict__ btot) {
    __shared__ int h[NB];
    int tid = threadIdx.x;
    if (tid < NB) h[tid] = 0;
    __syncthreads();
    int e0 = blockIdx.x * 4096;
    int e1 = min(e0 + 4096, N_EDGES);
    for (int e = e0 + tid; e < e1; e += 256)
        atomicAdd(&h[col[e] >> 8], 1);
    __syncthreads();
    if (tid < NB && h[tid]) atomicAdd(&btot[tid], h[tid]);
}

// ---------------- pass 0b: scan bucket totals -> bases + cursors ----------------

__global__ __launch_bounds__(256) void k_bucketscan(const int* __restrict__ btot,
                                                    int* __restrict__ bucketBase,
                                                    int* __restrict__ bucketCursor) {
    __shared__ int s[256];
    int tid = threadIdx.x;
    int v = (tid < NB) ? btot[tid] : 0;
    s[tid] = v;
    __syncthreads();
#pragma unroll
    for (int d = 1; d < 256; d <<= 1) {
        int t = (tid >= d) ? s[tid - d] : 0;
        __syncthreads();
        s[tid] += t;
        __syncthreads();
    }
    int excl = s[tid] - v;
    if (tid < NB) { bucketBase[tid] = excl; bucketCursor[tid] = excl; }
    if (tid == 0) bucketBase[NB] = N_EDGES;
}

// ---------------- pass 1: bin edges into bucket-contiguous staging ----------------
// Each block reserves one contiguous chunk per bucket -> single-writer cache lines.

__global__ __launch_bounds__(256) void k_binscatter(const int* __restrict__ row,
                                                    const int* __restrict__ col,
                                                    int* __restrict__ bucketCursor,
                                                    uint2* __restrict__ sedge) {
    __shared__ int hist[NB];
    __shared__ int chunkBase[NB];
    __shared__ int cur[NB];
    int tid = threadIdx.x;
    int e0 = blockIdx.x * CHUNK;
    int e1 = min(e0 + CHUNK, N_EDGES);
    if (tid < NB) { hist[tid] = 0; cur[tid] = 0; }
    __syncthreads();
    for (int e = e0 + tid; e < e1; e += 256)
        atomicAdd(&hist[col[e] >> 8], 1);
    __syncthreads();
    if (tid < NB)
        chunkBase[tid] = hist[tid] ? atomicAdd(&bucketCursor[tid], hist[tid]) : 0;
    __syncthreads();
    for (int e = e0 + tid; e < e1; e += 256) {
        int c = col[e];
        int b = c >> 8;
        int p = atomicAdd(&cur[b], 1);
        sedge[chunkBase[b] + p] = make_uint2((unsigned)row[e], (unsigned)c);
    }
}

// ---------------- pass 2: per-bucket counting sort; emits off[], dinv[], sorted[] ----------------

__global__ __launch_bounds__(256) void k_bucketsort(const uint2* __restrict__ sedge,
                                                    const int* __restrict__ bucketBase,
                                                    int* __restrict__ off,
                                                    float* __restrict__ dinv,
                                                    int* __restrict__ sorted) {
    __shared__ int hist[256];
    __shared__ int s[256];
    __shared__ int cur[256];
    int tid = threadIdx.x;
    int b = blockIdx.x;
    int base = bucketBase[b], end = bucketBase[b + 1];
    int col0 = b << 8;
    int ncol = min(256, N_NODES - col0);
    hist[tid] = 0;
    __syncthreads();
    for (int i = base + tid; i < end; i += 256)
        atomicAdd(&hist[sedge[i].y & 255], 1);
    __syncthreads();
    int v = hist[tid];
    s[tid] = v;
    __syncthreads();
#pragma unroll
    for (int d = 1; d < 256; d <<= 1) {
        int t = (tid >= d) ? s[tid - d] : 0;
        __syncthreads();
        s[tid] += t;
        __syncthreads();
    }
    int excl = s[tid] - v;
    cur[tid] = excl;
    if (tid < ncol) {
        off[col0 + tid] = base + excl;
        dinv[col0 + tid] = rsqrtf((float)(v + 1));   // +1 self-loop
    }
    if (b == NB - 1 && tid == 0) off[N_NODES] = N_EDGES;
    __syncthreads();
    for (int i = base + tid; i < end; i += 256) {
        uint2 e = sedge[i];
        int p = atomicAdd(&cur[e.y & 255], 1);
        sorted[base + p] = (int)e.x;
    }
}

// ---------------- W1 -> transposed f16 [HIDDEN][D_FEAT] ----------------

__global__ void k_convW1(const float* __restrict__ W, _Float16* __restrict__ Wt) {
    int i = blockIdx.x * 256 + threadIdx.x;
    if (i < D_FEAT * HIDDEN) {
        int n = i & 63, k = i >> 6;
        Wt[n * D_FEAT + k] = (_Float16)W[k * HIDDEN + n];
    }
}

// ---------------- GEMM1 (f16 MFMA): hs1[i,j] = f16((x[i,:] @ W1[:,j]) * dinv[i]) ----------------

#define LDA 72
#define LDB 72

__global__ __launch_bounds__(256) void k_gemm1(const float* __restrict__ X,
                                               const _Float16* __restrict__ Wt,
                                               const float* __restrict__ dinv,
                                               _Float16* __restrict__ out) {
    __shared__ _Float16 As[32 * LDA];
    __shared__ _Float16 Bs[64 * LDB];
    const int tid = threadIdx.x;
    const int wave = tid >> 6, lane = tid & 63;
    const int row0 = blockIdx.x * 32;
    const int m0 = (wave & 1) * 16, n0 = (wave >> 1) * 32;
    const int lr = lane & 15, quad = lane >> 4;

    const int ar = tid >> 3;
    const int ak = (tid & 7) * 8;
    const int bn = tid >> 2;
    const int bk = (tid & 3) * 16;

    f32x4 acc0 = {0.f, 0.f, 0.f, 0.f};
    f32x4 acc1 = {0.f, 0.f, 0.f, 0.f};

    for (int k0 = 0; k0 < D_FEAT; k0 += 64) {
        const float* xp = &X[(row0 + ar) * D_FEAT + k0 + ak];
        float4 v0 = *(const float4*)xp;
        float4 v1 = *(const float4*)(xp + 4);
        _Float16* ad = &As[ar * LDA + ak];
        ad[0] = (_Float16)v0.x; ad[1] = (_Float16)v0.y;
        ad[2] = (_Float16)v0.z; ad[3] = (_Float16)v0.w;
        ad[4] = (_Float16)v1.x; ad[5] = (_Float16)v1.y;
        ad[6] = (_Float16)v1.z; ad[7] = (_Float16)v1.w;
        const uint4* wp = (const uint4*)&Wt[bn * D_FEAT + k0 + bk];
        uint4 w0 = wp[0], w1 = wp[1];
        *(uint4*)&Bs[bn * LDB + bk] = w0;
        *(uint4*)&Bs[bn * LDB + bk + 8] = w1;
        __syncthreads();
#pragma unroll
        for (int kk = 0; kk < 64; kk += 32) {
            f16x8 a  = *(f16x8*)&As[(m0 + lr) * LDA + kk + quad * 8];
            f16x8 b0 = *(f16x8*)&Bs[(n0 + lr) * LDB + kk + quad * 8];
            f16x8 b1 = *(f16x8*)&Bs[(n0 + 16 + lr) * LDB + kk + quad * 8];
            acc0 = __builtin_amdgcn_mfma_f32_16x16x32_f16(a, b0, acc0, 0, 0, 0);
            acc1 = __builtin_amdgcn_mfma_f32_16x16x32_f16(a, b1, acc1, 0, 0, 0);
        }
        __syncthreads();
    }

#pragma unroll
    for (int r = 0; r < 4; ++r) {
        int m = row0 + m0 + quad * 4 + r;
        float dv = dinv[m];
        out[m * HIDDEN + n0 + lr]      = (_Float16)(acc0[r] * dv);
        out[m * HIDDEN + n0 + 16 + lr] = (_Float16)(acc1[r] * dv);
    }
}

// ---------------- gather 1: one wave per node, 2 edges/iter via half2 lanes ----------------

__global__ __launch_bounds__(256) void k_gather1(const int* __restrict__ off,
                                                 const int* __restrict__ sorted,
                                                 const _Float16* __restrict__ hs,
                                                 const float* __restrict__ dinv,
                                                 const float* __restrict__ bias,
                                                 float* __restrict__ out) {
    int node = (blockIdx.x * 256 + threadIdx.x) >> 6;
    int lane = threadIdx.x & 63;
    if (node >= N_NODES) return;
    int h = lane >> 5, fl = lane & 31;
    float ax = 0.f, ay = 0.f;
    if (h == 0) {
        f16x2 v = *(const f16x2*)&hs[node * HIDDEN + 2 * fl];
        ax = (float)v.x; ay = (float)v.y;
    }
    int beg = off[node], end = off[node + 1];
    int j = beg + h;
    for (; j + 2 < end; j += 4) {
        int s0 = sorted[j], s1 = sorted[j + 2];
        f16x2 v0 = *(const f16x2*)&hs[s0 * HIDDEN + 2 * fl];
        f16x2 v1 = *(const f16x2*)&hs[s1 * HIDDEN + 2 * fl];
        ax += (float)v0.x + (float)v1.x;
        ay += (float)v0.y + (float)v1.y;
    }
    for (; j < end; j += 2) {
        int s = sorted[j];
        f16x2 v = *(const f16x2*)&hs[s * HIDDEN + 2 * fl];
        ax += (float)v.x; ay += (float)v.y;
    }
    ax += __shfl_xor(ax, 32, 64);
    ay += __shfl_xor(ay, 32, 64);
    if (h == 0) {
        float dv = dinv[node];
        float2 o;
        o.x = fmaxf(fmaf(dv, ax, bias[2 * fl + 0]), 0.f);
        o.y = fmaxf(fmaf(dv, ay, bias[2 * fl + 1]), 0.f);
        *(float2*)&out[node * HIDDEN + 2 * fl] = o;
    }
}

// ---------------- GEMM2: hs2[n,c] = f16((a1[n,:] @ W2[:,c]) * dinv[n]) ----------------

__global__ __launch_bounds__(256) void k_gemm2(const float* __restrict__ A,
                                               const float* __restrict__ W,
                                               const float* __restrict__ dinv,
                                               _Float16* __restrict__ out) {
    __shared__ float Ws[HIDDEN * N_CLASSES];
    __shared__ float Aa[32][65];
    const int tid = threadIdx.x;
    const int node0 = blockIdx.x * 32;

    for (int i = tid; i < HIDDEN * N_CLASSES; i += 256) Ws[i] = W[i];
    for (int i = tid * 4; i < 32 * HIDDEN; i += 1024) {
        float4 v = *(const float4*)&A[node0 * HIDDEN + i];
        int n = i >> 6, k = i & 63;
        Aa[n][k + 0] = v.x; Aa[n][k + 1] = v.y; Aa[n][k + 2] = v.z; Aa[n][k + 3] = v.w;
    }
    __syncthreads();

    const int n = tid >> 3;
    const int c0 = (tid & 7) * 5;
    float acc[5] = {};
#pragma unroll
    for (int k = 0; k < HIDDEN; ++k) {
        float av = Aa[n][k];
#pragma unroll
        for (int j = 0; j < 5; ++j) acc[j] += av * Ws[k * N_CLASSES + c0 + j];
    }
    float dv = dinv[node0 + n];
#pragma unroll
    for (int j = 0; j < 5; ++j)
        out[(node0 + n) * N_CLASSES + c0 + j] = (_Float16)(acc[j] * dv);
}

// ---------------- gather 2 + epilogue + log-softmax ----------------

__global__ __launch_bounds__(256) void k_gather2_lsm(const int* __restrict__ off,
                                                     const int* __restrict__ sorted,
                                                     const _Float16* __restrict__ hs,
                                                     const float* __restrict__ dinv,
                                                     const float* __restrict__ bias,
                                                     float* __restrict__ out) {
    int node = (blockIdx.x * 256 + threadIdx.x) >> 6;
    int lane = threadIdx.x & 63;
    if (node >= N_NODES) return;
    int h = lane >> 5, fl = lane & 31;
    bool act = fl < 20;
    float ax = 0.f, ay = 0.f;
    if (h == 0 && act) {
        f16x2 v = *(const f16x2*)&hs[node * N_CLASSES + 2 * fl];
        ax = (float)v.x; ay = (float)v.y;
    }
    int beg = off[node], end = off[node + 1];
    int j = beg + h;
    for (; j + 2 < end; j += 4) {
        int s0 = sorted[j], s1 = sorted[j + 2];
        if (act) {
            f16x2 v0 = *(const f16x2*)&hs[s0 * N_CLASSES + 2 * fl];
            f16x2 v1 = *(const f16x2*)&hs[s1 * N_CLASSES + 2 * fl];
            ax += (float)v0.x + (float)v1.x;
            ay += (float)v0.y + (float)v1.y;
        }
    }
    for (; j < end; j += 2) {
        int s = sorted[j];
        if (act) {
            f16x2 v = *(const f16x2*)&hs[s * N_CLASSES + 2 * fl];
            ax += (float)v.x; ay += (float)v.y;
        }
    }
    ax += __shfl_xor(ax, 32, 64);
    ay += __shfl_xor(ay, 32, 64);
    float dv = dinv[node];
    float zx = act ? fmaf(dv, ax, bias[2 * fl + 0]) : -INFINITY;
    float zy = act ? fmaf(dv, ay, bias[2 * fl + 1]) : -INFINITY;
    float m = fmaxf(zx, zy);
#pragma unroll
    for (int d = 16; d > 0; d >>= 1) m = fmaxf(m, __shfl_xor(m, d, 64));
    float ex = act ? (expf(zx - m) + expf(zy - m)) : 0.f;
#pragma unroll
    for (int d = 16; d > 0; d >>= 1) ex += __shfl_xor(ex, d, 64);
    float lse = m + logf(ex);
    if (h == 0 && act) {
        float2 o; o.x = zx - lse; o.y = zy - lse;
        *(float2*)&out[node * N_CLASSES + 2 * fl] = o;
    }
}

// ---------------- launch ----------------

extern "C" void kernel_launch(void* const* d_in, const int* in_sizes, int n_in,
                              void* d_out, int out_size, void* d_ws, size_t ws_size,
                              hipStream_t stream) {
    const float* x  = (const float*)d_in[0];
    const int*   ei = (const int*)d_in[1];
    const float* W1 = (const float*)d_in[2];
    const float* b1 = (const float*)d_in[3];
    const float* W2 = (const float*)d_in[4];
    const float* b2 = (const float*)d_in[5];
    const int* row = ei;             // edge_index[0] = source
    const int* col = ei + N_EDGES;   // edge_index[1] = target

    char* ws = (char*)d_ws;
    int*      btot         = (int*)(ws + 0);            // 1 KB
    int*      bucketBase   = (int*)(ws + 1024);         // 1 KB (NB+1)
    int*      bucketCursor = (int*)(ws + 2048);         // 1 KB
    int*      off          = (int*)(ws + 4096);         // 160 KB + 4
    float*    dinv         = (float*)(ws + 172032);     // 160 KB
    uint2*    sedge        = (uint2*)(ws + 335872);     // 10.24 MB
    int*      sorted       = (int*)(ws + 10575872);     // 5.12 MB
    _Float16* W1t          = (_Float16*)(ws + 15695872);// 128 KB
    _Float16* B1           = (_Float16*)(ws + 15826944);// 5.12 MB : hs1 f16
    float*    B2           = (float*)(ws + 20946944);   // 10.24 MB : a1 fp32
    _Float16* B3           = (_Float16*)(ws + 31186944);// 3.2 MB : hs2 f16

    hipMemsetAsync(btot, 0, NB * sizeof(int), stream);
    k_binhist<<<(N_EDGES + 4095) / 4096, 256, 0, stream>>>(col, btot);
    k_bucketscan<<<1, 256, 0, stream>>>(btot, bucketBase, bucketCursor);
    k_binscatter<<<(N_EDGES + CHUNK - 1) / CHUNK, 256, 0, stream>>>(row, col, bucketCursor, sedge);
    k_bucketsort<<<NB, 256, 0, stream>>>(sedge, bucketBase, off, dinv, sorted);

    k_convW1<<<(D_FEAT * HIDDEN) / 256, 256, 0, stream>>>(W1, W1t);
    k_gemm1<<<N_NODES / 32, 256, 0, stream>>>(x, W1t, dinv, B1);
    k_gather1<<<(N_NODES + 3) / 4, 256, 0, stream>>>(off, sorted, B1, dinv, b1, B2);

    k_gemm2<<<N_NODES / 32, 256, 0, stream>>>(B2, W2, dinv, B3);
    k_gather2_lsm<<<(N_NODES + 3) / 4, 256, 0, stream>>>(off, sorted, B3, dinv, b2, (float*)d_out);
}

// Round 5
// 409.790 us; speedup vs baseline: 5.5526x; 1.0428x over previous
//
#include <hip/hip_runtime.h>
#include <hip/hip_bf16.h>
#include <math.h>

#define N_NODES 40000
#define N_EDGES 1280000
#define D_FEAT 1024
#define HIDDEN 64
#define N_CLASSES 40
#define NB 157            // buckets of 256 destination cols: ceil(40000/256)
#define CHUNK 8192        // edges per k_binscatter block

typedef _Float16 f16x8 __attribute__((ext_vector_type(8)));
typedef _Float16 f16x2 __attribute__((ext_vector_type(2)));
typedef float f32x4 __attribute__((ext_vector_type(4)));

// ---------------- fused pass 0: bucket histogram + W1 transpose/convert ----------------

#define HIST_BLOCKS 313   // ceil(1280000/4096)
#define CONV_BLOCKS 256   // 65536/256

__global__ __launch_bounds__(256) void k_pre(const int* __restrict__ col,
                                             int* __restrict__ btot,
                                             const float* __restrict__ W,
                                             _Float16* __restrict__ Wt) {
    __shared__ int h[NB];
    int tid = threadIdx.x;
    if (blockIdx.x < HIST_BLOCKS) {
        if (tid < NB) h[tid] = 0;
        __syncthreads();
        int e0 = blockIdx.x * 4096;
        int e1 = min(e0 + 4096, N_EDGES);
        for (int e = e0 + tid; e < e1; e += 256)
            atomicAdd(&h[col[e] >> 8], 1);
        __syncthreads();
        if (tid < NB && h[tid]) atomicAdd(&btot[tid], h[tid]);
    } else {
        int i = (blockIdx.x - HIST_BLOCKS) * 256 + tid;
        int n = i & 63, k = i >> 6;
        Wt[n * D_FEAT + k] = (_Float16)W[k * HIDDEN + n];
    }
}

// ---------------- pass 0b: scan bucket totals -> bases + cursors ----------------

__global__ __launch_bounds__(256) void k_bucketscan(const int* __restrict__ btot,
                                                    int* __restrict__ bucketBase,
                                                    int* __restrict__ bucketCursor) {
    __shared__ int s[256];
    int tid = threadIdx.x;
    int v = (tid < NB) ? btot[tid] : 0;
    s[tid] = v;
    __syncthreads();
#pragma unroll
    for (int d = 1; d < 256; d <<= 1) {
        int t = (tid >= d) ? s[tid - d] : 0;
        __syncthreads();
        s[tid] += t;
        __syncthreads();
    }
    int excl = s[tid] - v;
    if (tid < NB) { bucketBase[tid] = excl; bucketCursor[tid] = excl; }
    if (tid == 0) bucketBase[NB] = N_EDGES;
}

// ---------------- pass 1: bin edges into bucket-contiguous staging ----------------

__global__ __launch_bounds__(256) void k_binscatter(const int* __restrict__ row,
                                                    const int* __restrict__ col,
                                                    int* __restrict__ bucketCursor,
                                                    uint2* __restrict__ sedge) {
    __shared__ int hist[NB];
    __shared__ int chunkBase[NB];
    __shared__ int cur[NB];
    int tid = threadIdx.x;
    int e0 = blockIdx.x * CHUNK;
    int e1 = min(e0 + CHUNK, N_EDGES);
    if (tid < NB) { hist[tid] = 0; cur[tid] = 0; }
    __syncthreads();
    for (int e = e0 + tid; e < e1; e += 256)
        atomicAdd(&hist[col[e] >> 8], 1);
    __syncthreads();
    if (tid < NB)
        chunkBase[tid] = hist[tid] ? atomicAdd(&bucketCursor[tid], hist[tid]) : 0;
    __syncthreads();
    for (int e = e0 + tid; e < e1; e += 256) {
        int c = col[e];
        int b = c >> 8;
        int p = atomicAdd(&cur[b], 1);
        sedge[chunkBase[b] + p] = make_uint2((unsigned)row[e], (unsigned)c);
    }
}

// ---------------- pass 2: per-bucket counting sort; emits off[], dinv[], sorted[] ----------------

__global__ __launch_bounds__(256) void k_bucketsort(const uint2* __restrict__ sedge,
                                                    const int* __restrict__ bucketBase,
                                                    int* __restrict__ off,
                                                    float* __restrict__ dinv,
                                                    int* __restrict__ sorted) {
    __shared__ int hist[256];
    __shared__ int s[256];
    __shared__ int cur[256];
    int tid = threadIdx.x;
    int b = blockIdx.x;
    int base = bucketBase[b], end = bucketBase[b + 1];
    int col0 = b << 8;
    int ncol = min(256, N_NODES - col0);
    hist[tid] = 0;
    __syncthreads();
    for (int i = base + tid; i < end; i += 256)
        atomicAdd(&hist[sedge[i].y & 255], 1);
    __syncthreads();
    int v = hist[tid];
    s[tid] = v;
    __syncthreads();
#pragma unroll
    for (int d = 1; d < 256; d <<= 1) {
        int t = (tid >= d) ? s[tid - d] : 0;
        __syncthreads();
        s[tid] += t;
        __syncthreads();
    }
    int excl = s[tid] - v;
    cur[tid] = excl;
    if (tid < ncol) {
        off[col0 + tid] = base + excl;
        dinv[col0 + tid] = rsqrtf((float)(v + 1));   // +1 self-loop
    }
    if (b == NB - 1 && tid == 0) off[N_NODES] = N_EDGES;
    __syncthreads();
    for (int i = base + tid; i < end; i += 256) {
        uint2 e = sedge[i];
        int p = atomicAdd(&cur[e.y & 255], 1);
        sorted[base + p] = (int)e.x;
    }
}

// ---------------- GEMM1 (f16 MFMA): hs1[i,j] = f16((x[i,:] @ W1[:,j]) * dinv[i]) ----------------
// 64x64 tile per 256-thread block (625 blocks), BK=64, 4 waves each 16x64.
// Staging: packed f16x8 16B LDS writes (2/thread for A, 2/thread for B per K-step).

#define LDA 72
#define LDB 72

__global__ __launch_bounds__(256) void k_gemm1(const float* __restrict__ X,
                                               const _Float16* __restrict__ Wt,
                                               const float* __restrict__ dinv,
                                               _Float16* __restrict__ out) {
    __shared__ _Float16 As[64 * LDA];
    __shared__ _Float16 Bs[64 * LDB];
    const int tid = threadIdx.x;
    const int wave = tid >> 6, lane = tid & 63;
    const int row0 = blockIdx.x * 64;
    const int m0 = wave * 16;
    const int lr = lane & 15, quad = lane >> 4;

    const int ar = tid >> 2;          // 0..63 tile row
    const int ak = (tid & 3) * 16;    // K offset (16 elements)

    f32x4 acc0 = {0.f,0.f,0.f,0.f}, acc1 = {0.f,0.f,0.f,0.f};
    f32x4 acc2 = {0.f,0.f,0.f,0.f}, acc3 = {0.f,0.f,0.f,0.f};

    for (int k0 = 0; k0 < D_FEAT; k0 += 64) {
        const float* xp = &X[(row0 + ar) * D_FEAT + k0 + ak];
        float4 v0 = *(const float4*)(xp + 0);
        float4 v1 = *(const float4*)(xp + 4);
        float4 v2 = *(const float4*)(xp + 8);
        float4 v3 = *(const float4*)(xp + 12);
        f16x8 p0 = {(_Float16)v0.x,(_Float16)v0.y,(_Float16)v0.z,(_Float16)v0.w,
                    (_Float16)v1.x,(_Float16)v1.y,(_Float16)v1.z,(_Float16)v1.w};
        f16x8 p1 = {(_Float16)v2.x,(_Float16)v2.y,(_Float16)v2.z,(_Float16)v2.w,
                    (_Float16)v3.x,(_Float16)v3.y,(_Float16)v3.z,(_Float16)v3.w};
        *(f16x8*)&As[ar * LDA + ak]     = p0;
        *(f16x8*)&As[ar * LDA + ak + 8] = p1;
        const uint4* wp = (const uint4*)&Wt[ar * D_FEAT + k0 + ak];
        uint4 w0 = wp[0], w1 = wp[1];
        *(uint4*)&Bs[ar * LDB + ak]     = w0;
        *(uint4*)&Bs[ar * LDB + ak + 8] = w1;
        __syncthreads();
#pragma unroll
        for (int kk = 0; kk < 64; kk += 32) {
            f16x8 a  = *(f16x8*)&As[(m0 + lr) * LDA + kk + quad * 8];
            f16x8 b0 = *(f16x8*)&Bs[( 0 + lr) * LDB + kk + quad * 8];
            f16x8 b1 = *(f16x8*)&Bs[(16 + lr) * LDB + kk + quad * 8];
            f16x8 b2 = *(f16x8*)&Bs[(32 + lr) * LDB + kk + quad * 8];
            f16x8 b3 = *(f16x8*)&Bs[(48 + lr) * LDB + kk + quad * 8];
            acc0 = __builtin_amdgcn_mfma_f32_16x16x32_f16(a, b0, acc0, 0, 0, 0);
            acc1 = __builtin_amdgcn_mfma_f32_16x16x32_f16(a, b1, acc1, 0, 0, 0);
            acc2 = __builtin_amdgcn_mfma_f32_16x16x32_f16(a, b2, acc2, 0, 0, 0);
            acc3 = __builtin_amdgcn_mfma_f32_16x16x32_f16(a, b3, acc3, 0, 0, 0);
        }
        __syncthreads();
    }

#pragma unroll
    for (int r = 0; r < 4; ++r) {
        int m = row0 + m0 + quad * 4 + r;
        float dv = dinv[m];
        out[m * HIDDEN +  0 + lr] = (_Float16)(acc0[r] * dv);
        out[m * HIDDEN + 16 + lr] = (_Float16)(acc1[r] * dv);
        out[m * HIDDEN + 32 + lr] = (_Float16)(acc2[r] * dv);
        out[m * HIDDEN + 48 + lr] = (_Float16)(acc3[r] * dv);
    }
}

// ---------------- fused gather1 + gemm2 ----------------
// 4 nodes per 256-thread block (wave = node). Phase 1: gather a1 into LDS.
// Phase 2: hs2[n,c] = f16((a1[n,:] @ W2[:,c]) * dinv[n]) straight to B3.

__global__ __launch_bounds__(256) void k_g1g2(const int* __restrict__ off,
                                              const int* __restrict__ sorted,
                                              const _Float16* __restrict__ hs,
                                              const float* __restrict__ dinv,
                                              const float* __restrict__ bias,
                                              const float* __restrict__ W2,
                                              _Float16* __restrict__ B3) {
    __shared__ float W2t[N_CLASSES][65];   // [c][k], pad 65 -> conflict-free
    __shared__ float a1s[4][64];
    const int tid = threadIdx.x;
    const int wave = tid >> 6, lane = tid & 63;
    const int node = blockIdx.x * 4 + wave;

    for (int i = tid; i < HIDDEN * N_CLASSES; i += 256)
        W2t[i % N_CLASSES][i / N_CLASSES] = W2[i];

    // ---- phase 1: gather (2 feature-halves × 4-deep MLP) ----
    int h = lane >> 5, fl = lane & 31;
    float ax = 0.f, ay = 0.f;
    if (h == 0) {
        f16x2 v = *(const f16x2*)&hs[node * HIDDEN + 2 * fl];
        ax = (float)v.x; ay = (float)v.y;
    }
    int beg = off[node], end = off[node + 1];
    int j = beg + h;
    for (; j + 6 < end; j += 8) {
        int s0 = sorted[j], s1 = sorted[j + 2], s2 = sorted[j + 4], s3 = sorted[j + 6];
        f16x2 v0 = *(const f16x2*)&hs[s0 * HIDDEN + 2 * fl];
        f16x2 v1 = *(const f16x2*)&hs[s1 * HIDDEN + 2 * fl];
        f16x2 v2 = *(const f16x2*)&hs[s2 * HIDDEN + 2 * fl];
        f16x2 v3 = *(const f16x2*)&hs[s3 * HIDDEN + 2 * fl];
        ax += (float)v0.x + (float)v1.x + (float)v2.x + (float)v3.x;
        ay += (float)v0.y + (float)v1.y + (float)v2.y + (float)v3.y;
    }
    for (; j < end; j += 2) {
        int s = sorted[j];
        f16x2 v = *(const f16x2*)&hs[s * HIDDEN + 2 * fl];
        ax += (float)v.x; ay += (float)v.y;
    }
    ax += __shfl_xor(ax, 32, 64);
    ay += __shfl_xor(ay, 32, 64);
    float dv = dinv[node];
    if (h == 0) {
        float2 o;
        o.x = fmaxf(fmaf(dv, ax, bias[2 * fl + 0]), 0.f);
        o.y = fmaxf(fmaf(dv, ay, bias[2 * fl + 1]), 0.f);
        *(float2*)&a1s[wave][2 * fl] = o;
    }
    __syncthreads();

    // ---- phase 2: per-node 64x40 matvec ----
    if (lane < N_CLASSES) {
        float acc = 0.f;
#pragma unroll
        for (int k = 0; k < HIDDEN; ++k)
            acc = fmaf(a1s[wave][k], W2t[lane][k], acc);
        B3[node * N_CLASSES + lane] = (_Float16)(acc * dv);
    }
}

// ---------------- gather 2 + epilogue + log-softmax ----------------

__global__ __launch_bounds__(256) void k_gather2_lsm(const int* __restrict__ off,
                                                     const int* __restrict__ sorted,
                                                     const _Float16* __restrict__ hs,
                                                     const float* __restrict__ dinv,
                                                     const float* __restrict__ bias,
                                                     float* __restrict__ out) {
    int node = (blockIdx.x * 256 + threadIdx.x) >> 6;
    int lane = threadIdx.x & 63;
    if (node >= N_NODES) return;
    int h = lane >> 5, fl = lane & 31;
    bool act = fl < 20;
    float ax = 0.f, ay = 0.f;
    if (h == 0 && act) {
        f16x2 v = *(const f16x2*)&hs[node * N_CLASSES + 2 * fl];
        ax = (float)v.x; ay = (float)v.y;
    }
    int beg = off[node], end = off[node + 1];
    int j = beg + h;
    for (; j + 6 < end; j += 8) {
        int s0 = sorted[j], s1 = sorted[j + 2], s2 = sorted[j + 4], s3 = sorted[j + 6];
        if (act) {
            f16x2 v0 = *(const f16x2*)&hs[s0 * N_CLASSES + 2 * fl];
            f16x2 v1 = *(const f16x2*)&hs[s1 * N_CLASSES + 2 * fl];
            f16x2 v2 = *(const f16x2*)&hs[s2 * N_CLASSES + 2 * fl];
            f16x2 v3 = *(const f16x2*)&hs[s3 * N_CLASSES + 2 * fl];
            ax += (float)v0.x + (float)v1.x + (float)v2.x + (float)v3.x;
            ay += (float)v0.y + (float)v1.y + (float)v2.y + (float)v3.y;
        }
    }
    for (; j < end; j += 2) {
        int s = sorted[j];
        if (act) {
            f16x2 v = *(const f16x2*)&hs[s * N_CLASSES + 2 * fl];
            ax += (float)v.x; ay += (float)v.y;
        }
    }
    ax += __shfl_xor(ax, 32, 64);
    ay += __shfl_xor(ay, 32, 64);
    float dv = dinv[node];
    float zx = act ? fmaf(dv, ax, bias[2 * fl + 0]) : -INFINITY;
    float zy = act ? fmaf(dv, ay, bias[2 * fl + 1]) : -INFINITY;
    float m = fmaxf(zx, zy);
#pragma unroll
    for (int d = 16; d > 0; d >>= 1) m = fmaxf(m, __shfl_xor(m, d, 64));
    float ex = act ? (expf(zx - m) + expf(zy - m)) : 0.f;
#pragma unroll
    for (int d = 16; d > 0; d >>= 1) ex += __shfl_xor(ex, d, 64);
    float lse = m + logf(ex);
    if (h == 0 && act) {
        float2 o; o.x = zx - lse; o.y = zy - lse;
        *(float2*)&out[node * N_CLASSES + 2 * fl] = o;
    }
}

// ---------------- launch ----------------

extern "C" void kernel_launch(void* const* d_in, const int* in_sizes, int n_in,
                              void* d_out, int out_size, void* d_ws, size_t ws_size,
                              hipStream_t stream) {
    const float* x  = (const float*)d_in[0];
    const int*   ei = (const int*)d_in[1];
    const float* W1 = (const float*)d_in[2];
    const float* b1 = (const float*)d_in[3];
    const float* W2 = (const float*)d_in[4];
    const float* b2 = (const float*)d_in[5];
    const int* row = ei;             // edge_index[0] = source
    const int* col = ei + N_EDGES;   // edge_index[1] = target

    char* ws = (char*)d_ws;
    int*      btot         = (int*)(ws + 0);            // 1 KB
    int*      bucketBase   = (int*)(ws + 1024);         // 1 KB (NB+1)
    int*      bucketCursor = (int*)(ws + 2048);         // 1 KB
    int*      off          = (int*)(ws + 4096);         // 160 KB + 4
    float*    dinv         = (float*)(ws + 172032);     // 160 KB
    uint2*    sedge        = (uint2*)(ws + 335872);     // 10.24 MB
    int*      sorted       = (int*)(ws + 10575872);     // 5.12 MB
    _Float16* W1t          = (_Float16*)(ws + 15695872);// 128 KB
    _Float16* B1           = (_Float16*)(ws + 15826944);// 5.12 MB : hs1 f16
    _Float16* B3           = (_Float16*)(ws + 20946944);// 3.2 MB : hs2 f16

    hipMemsetAsync(btot, 0, NB * sizeof(int), stream);
    k_pre<<<HIST_BLOCKS + CONV_BLOCKS, 256, 0, stream>>>(col, btot, W1, W1t);
    k_bucketscan<<<1, 256, 0, stream>>>(btot, bucketBase, bucketCursor);
    k_binscatter<<<(N_EDGES + CHUNK - 1) / CHUNK, 256, 0, stream>>>(row, col, bucketCursor, sedge);
    k_bucketsort<<<NB, 256, 0, stream>>>(sedge, bucketBase, off, dinv, sorted);

    k_gemm1<<<N_NODES / 64, 256, 0, stream>>>(x, W1t, dinv, B1);
    k_g1g2<<<N_NODES / 4, 256, 0, stream>>>(off, sorted, B1, dinv, b1, W2, B3);
    k_gather2_lsm<<<(N_NODES + 3) / 4, 256, 0, stream>>>(off, sorted, B3, dinv, b2, (float*)d_out);
}

// Round 6
// 385.054 us; speedup vs baseline: 5.9093x; 1.0642x over previous
//
#include <hip/hip_runtime.h>
#include <hip/hip_bf16.h>
#include <math.h>

#define N_NODES 40000
#define N_EDGES 1280000
#define D_FEAT 1024
#define HIDDEN 64
#define N_CLASSES 40
#define NB 157            // buckets of 256 destination cols: ceil(40000/256)
#define CHUNK 4096        // edges per k_binscatter block (16 per thread)

typedef _Float16 f16x8 __attribute__((ext_vector_type(8)));
typedef _Float16 f16x2 __attribute__((ext_vector_type(2)));
typedef float f32x4 __attribute__((ext_vector_type(4)));

// ---------------- fused pass 0: bucket histogram + W1 transpose/convert ----------------

#define HIST_BLOCKS 313   // ceil(1280000/4096)
#define CONV_BLOCKS 256   // 65536/256

__global__ __launch_bounds__(256) void k_pre(const int* __restrict__ col,
                                             int* __restrict__ btot,
                                             const float* __restrict__ W,
                                             _Float16* __restrict__ Wt) {
    __shared__ int h[NB];
    int tid = threadIdx.x;
    if (blockIdx.x < HIST_BLOCKS) {
        if (tid < NB) h[tid] = 0;
        __syncthreads();
        int e0 = blockIdx.x * 4096;
        int e1 = min(e0 + 4096, N_EDGES);
        for (int e = e0 + tid; e < e1; e += 256)
            atomicAdd(&h[col[e] >> 8], 1);
        __syncthreads();
        if (tid < NB && h[tid]) atomicAdd(&btot[tid], h[tid]);
    } else {
        int i = (blockIdx.x - HIST_BLOCKS) * 256 + tid;
        int n = i & 63, k = i >> 6;
        Wt[n * D_FEAT + k] = (_Float16)W[k * HIDDEN + n];
    }
}

// ---------------- pass 1: bin edges, bucket-ordered in LDS, coalesced flush ----------------
// sedge element: (col&255)<<16 | row   (row < 40000 < 2^16)

__global__ __launch_bounds__(256) void k_binscatter(const int* __restrict__ row,
                                                    const int* __restrict__ col,
                                                    const int* __restrict__ btot,
                                                    int* __restrict__ gcur,
                                                    unsigned* __restrict__ sedge) {
    __shared__ unsigned stage[CHUNK];
    __shared__ unsigned char bo[CHUNK];
    __shared__ int sc[256];
    __shared__ int bb[NB];
    __shared__ int hist[NB];
    __shared__ int lo[NB];
    __shared__ int cur[NB];
    __shared__ int dst[NB];
    const int tid = threadIdx.x;
    const int e0 = blockIdx.x * CHUNK;
    const int nE = min(CHUNK, N_EDGES - e0);

    if (tid < NB) { hist[tid] = 0; cur[tid] = 0; }
    int bv = (tid < NB) ? btot[tid] : 0;
    sc[tid] = bv;
    __syncthreads();
#pragma unroll
    for (int d = 1; d < 256; d <<= 1) {
        int t = (tid >= d) ? sc[tid - d] : 0;
        __syncthreads();
        sc[tid] += t;
        __syncthreads();
    }
    if (tid < NB) bb[tid] = sc[tid] - bv;   // exclusive bucket base (global)

    int c[16];
#pragma unroll
    for (int t = 0; t < 16; ++t) {
        int e = tid + t * 256;
        c[t] = (e < nE) ? col[e0 + e] : -1;
        if (e < nE) atomicAdd(&hist[c[t] >> 8], 1);
    }
    __syncthreads();

    int hv = (tid < NB) ? hist[tid] : 0;
    sc[tid] = hv;
    __syncthreads();
#pragma unroll
    for (int d = 1; d < 256; d <<= 1) {
        int t = (tid >= d) ? sc[tid - d] : 0;
        __syncthreads();
        sc[tid] += t;
        __syncthreads();
    }
    if (tid < NB) {
        int excl = sc[tid] - hv;
        lo[tid] = excl;
        int cp = hv ? atomicAdd(&gcur[tid], hv) : 0;
        dst[tid] = bb[tid] + cp - excl;     // global addr = dst[b] + ldsIdx
    }
    __syncthreads();

#pragma unroll
    for (int t = 0; t < 16; ++t) {
        int e = tid + t * 256;
        if (e < nE) {
            int b = c[t] >> 8;
            int p = lo[b] + atomicAdd(&cur[b], 1);
            stage[p] = ((unsigned)(c[t] & 255) << 16) | (unsigned)row[e0 + e];
            bo[p] = (unsigned char)b;
        }
    }
    __syncthreads();
    for (int i = tid; i < nE; i += 256)
        sedge[dst[bo[i]] + i] = stage[i];   // coalesced: consecutive i -> consecutive addr per run
}

// ---------------- pass 2: per-bucket counting sort; emits off[], dinv[], sorted[] (u16) ----------------

__global__ __launch_bounds__(256) void k_bucketsort(const unsigned* __restrict__ sedge,
                                                    const int* __restrict__ btot,
                                                    int* __restrict__ off,
                                                    float* __restrict__ dinv,
                                                    unsigned short* __restrict__ sorted) {
    __shared__ int sc[256];
    __shared__ int hist[256];
    __shared__ int cur[256];
    const int tid = threadIdx.x;
    const int b = blockIdx.x;
    int bv = (tid < NB) ? btot[tid] : 0;
    sc[tid] = bv;
    hist[tid] = 0;
    __syncthreads();
#pragma unroll
    for (int d = 1; d < 256; d <<= 1) {
        int t = (tid >= d) ? sc[tid - d] : 0;
        __syncthreads();
        sc[tid] += t;
        __syncthreads();
    }
    const int base = (b == 0) ? 0 : sc[b - 1];
    const int end  = sc[b];
    __syncthreads();

    for (int i = base + tid; i < end; i += 256)
        atomicAdd(&hist[sedge[i] >> 16], 1);
    __syncthreads();
    int v = hist[tid];
    sc[tid] = v;
    __syncthreads();
#pragma unroll
    for (int d = 1; d < 256; d <<= 1) {
        int t = (tid >= d) ? sc[tid - d] : 0;
        __syncthreads();
        sc[tid] += t;
        __syncthreads();
    }
    int excl = sc[tid] - v;
    cur[tid] = excl;
    int col0 = b << 8;
    int ncol = min(256, N_NODES - col0);
    if (tid < ncol) {
        off[col0 + tid] = base + excl;
        dinv[col0 + tid] = rsqrtf((float)(v + 1));   // +1 self-loop
    }
    if (b == NB - 1 && tid == 0) off[N_NODES] = N_EDGES;
    __syncthreads();
    for (int i = base + tid; i < end; i += 256) {
        unsigned e = sedge[i];
        int p = atomicAdd(&cur[e >> 16], 1);
        sorted[base + p] = (unsigned short)e;
    }
}

// ---------------- GEMM1 (f16 MFMA): hs1[i,j] = f16((x[i,:] @ W1[:,j]) * dinv[i]) ----------------
// 32x64 tile per 256-thread block (1250 blocks), BK=64, packed f16x8 staging.

#define LDA 72
#define LDB 72

__global__ __launch_bounds__(256) void k_gemm1(const float* __restrict__ X,
                                               const _Float16* __restrict__ Wt,
                                               const float* __restrict__ dinv,
                                               _Float16* __restrict__ out) {
    __shared__ _Float16 As[32 * LDA];
    __shared__ _Float16 Bs[64 * LDB];
    const int tid = threadIdx.x;
    const int wave = tid >> 6, lane = tid & 63;
    const int row0 = blockIdx.x * 32;
    const int m0 = (wave & 1) * 16, n0 = (wave >> 1) * 32;
    const int lr = lane & 15, quad = lane >> 4;

    const int ar = tid >> 3;          // 0..31 A row
    const int ak = (tid & 7) * 8;     // K offset (8 floats)
    const int bn = tid >> 2;          // 0..63 B row (n)
    const int bk = (tid & 3) * 16;    // K offset (16 halves)

    f32x4 acc0 = {0.f,0.f,0.f,0.f}, acc1 = {0.f,0.f,0.f,0.f};

    for (int k0 = 0; k0 < D_FEAT; k0 += 64) {
        const float* xp = &X[(row0 + ar) * D_FEAT + k0 + ak];
        float4 v0 = *(const float4*)(xp + 0);
        float4 v1 = *(const float4*)(xp + 4);
        f16x8 p0 = {(_Float16)v0.x,(_Float16)v0.y,(_Float16)v0.z,(_Float16)v0.w,
                    (_Float16)v1.x,(_Float16)v1.y,(_Float16)v1.z,(_Float16)v1.w};
        *(f16x8*)&As[ar * LDA + ak] = p0;
        const uint4* wp = (const uint4*)&Wt[bn * D_FEAT + k0 + bk];
        uint4 w0 = wp[0], w1 = wp[1];
        *(uint4*)&Bs[bn * LDB + bk]     = w0;
        *(uint4*)&Bs[bn * LDB + bk + 8] = w1;
        __syncthreads();
#pragma unroll
        for (int kk = 0; kk < 64; kk += 32) {
            f16x8 a  = *(f16x8*)&As[(m0 + lr) * LDA + kk + quad * 8];
            f16x8 b0 = *(f16x8*)&Bs[(n0 + lr) * LDB + kk + quad * 8];
            f16x8 b1 = *(f16x8*)&Bs[(n0 + 16 + lr) * LDB + kk + quad * 8];
            acc0 = __builtin_amdgcn_mfma_f32_16x16x32_f16(a, b0, acc0, 0, 0, 0);
            acc1 = __builtin_amdgcn_mfma_f32_16x16x32_f16(a, b1, acc1, 0, 0, 0);
        }
        __syncthreads();
    }

#pragma unroll
    for (int r = 0; r < 4; ++r) {
        int m = row0 + m0 + quad * 4 + r;
        float dv = dinv[m];
        out[m * HIDDEN + n0 + lr]      = (_Float16)(acc0[r] * dv);
        out[m * HIDDEN + n0 + 16 + lr] = (_Float16)(acc1[r] * dv);
    }
}

// ---------------- fused gather1 + gemm2 ----------------
// 4 nodes per block (wave = node). Edge indices loaded 64-at-a-time, broadcast by shfl.

__global__ __launch_bounds__(256) void k_g1g2(const int* __restrict__ off,
                                              const unsigned short* __restrict__ sorted,
                                              const _Float16* __restrict__ hs,
                                              const float* __restrict__ dinv,
                                              const float* __restrict__ bias,
                                              const float* __restrict__ W2,
                                              _Float16* __restrict__ B3) {
    __shared__ float W2t[N_CLASSES][65];
    __shared__ float a1s[4][64];
    const int tid = threadIdx.x;
    const int wave = tid >> 6, lane = tid & 63;
    const int node = blockIdx.x * 4 + wave;

    for (int i = tid; i < HIDDEN * N_CLASSES; i += 256)
        W2t[i % N_CLASSES][i / N_CLASSES] = W2[i];

    int h = lane >> 5, fl = lane & 31;
    float ax = 0.f, ay = 0.f;
    if (h == 0) {
        f16x2 v = *(const f16x2*)&hs[node * HIDDEN + 2 * fl];
        ax = (float)v.x; ay = (float)v.y;
    }
    int beg = off[node], end = off[node + 1];
    for (int base = beg; base < end; base += 64) {
        int m = end - base; if (m > 64) m = 64;
        int vidx = (lane < m) ? (int)sorted[base + lane] : 0;
        int i = h;
        for (; i + 6 < m; i += 8) {
            int s0 = __shfl(vidx, i,     64);
            int s1 = __shfl(vidx, i + 2, 64);
            int s2 = __shfl(vidx, i + 4, 64);
            int s3 = __shfl(vidx, i + 6, 64);
            f16x2 v0 = *(const f16x2*)&hs[s0 * HIDDEN + 2 * fl];
            f16x2 v1 = *(const f16x2*)&hs[s1 * HIDDEN + 2 * fl];
            f16x2 v2 = *(const f16x2*)&hs[s2 * HIDDEN + 2 * fl];
            f16x2 v3 = *(const f16x2*)&hs[s3 * HIDDEN + 2 * fl];
            ax += (float)v0.x + (float)v1.x + (float)v2.x + (float)v3.x;
            ay += (float)v0.y + (float)v1.y + (float)v2.y + (float)v3.y;
        }
        for (; i < m; i += 2) {
            int s = __shfl(vidx, i, 64);
            f16x2 v = *(const f16x2*)&hs[s * HIDDEN + 2 * fl];
            ax += (float)v.x; ay += (float)v.y;
        }
    }
    ax += __shfl_xor(ax, 32, 64);
    ay += __shfl_xor(ay, 32, 64);
    float dv = dinv[node];
    if (h == 0) {
        float2 o;
        o.x = fmaxf(fmaf(dv, ax, bias[2 * fl + 0]), 0.f);
        o.y = fmaxf(fmaf(dv, ay, bias[2 * fl + 1]), 0.f);
        *(float2*)&a1s[wave][2 * fl] = o;
    }
    __syncthreads();

    if (lane < N_CLASSES) {
        float acc = 0.f;
#pragma unroll
        for (int k = 0; k < HIDDEN; ++k)
            acc = fmaf(a1s[wave][k], W2t[lane][k], acc);
        B3[node * N_CLASSES + lane] = (_Float16)(acc * dv);
    }
}

// ---------------- gather 2 + epilogue + log-softmax ----------------

__global__ __launch_bounds__(256) void k_gather2_lsm(const int* __restrict__ off,
                                                     const unsigned short* __restrict__ sorted,
                                                     const _Float16* __restrict__ hs,
                                                     const float* __restrict__ dinv,
                                                     const float* __restrict__ bias,
                                                     float* __restrict__ out) {
    int node = (blockIdx.x * 256 + threadIdx.x) >> 6;
    int lane = threadIdx.x & 63;
    if (node >= N_NODES) return;
    int h = lane >> 5, fl = lane & 31;
    bool act = fl < 20;
    float ax = 0.f, ay = 0.f;
    if (h == 0 && act) {
        f16x2 v = *(const f16x2*)&hs[node * N_CLASSES + 2 * fl];
        ax = (float)v.x; ay = (float)v.y;
    }
    int beg = off[node], end = off[node + 1];
    for (int base = beg; base < end; base += 64) {
        int m = end - base; if (m > 64) m = 64;
        int vidx = (lane < m) ? (int)sorted[base + lane] : 0;
        int i = h;
        for (; i + 6 < m; i += 8) {
            int s0 = __shfl(vidx, i,     64);
            int s1 = __shfl(vidx, i + 2, 64);
            int s2 = __shfl(vidx, i + 4, 64);
            int s3 = __shfl(vidx, i + 6, 64);
            if (act) {
                f16x2 v0 = *(const f16x2*)&hs[s0 * N_CLASSES + 2 * fl];
                f16x2 v1 = *(const f16x2*)&hs[s1 * N_CLASSES + 2 * fl];
                f16x2 v2 = *(const f16x2*)&hs[s2 * N_CLASSES + 2 * fl];
                f16x2 v3 = *(const f16x2*)&hs[s3 * N_CLASSES + 2 * fl];
                ax += (float)v0.x + (float)v1.x + (float)v2.x + (float)v3.x;
                ay += (float)v0.y + (float)v1.y + (float)v2.y + (float)v3.y;
            }
        }
        for (; i < m; i += 2) {
            int s = __shfl(vidx, i, 64);
            if (act) {
                f16x2 v = *(const f16x2*)&hs[s * N_CLASSES + 2 * fl];
                ax += (float)v.x; ay += (float)v.y;
            }
        }
    }
    ax += __shfl_xor(ax, 32, 64);
    ay += __shfl_xor(ay, 32, 64);
    float dv = dinv[node];
    float zx = act ? fmaf(dv, ax, bias[2 * fl + 0]) : -INFINITY;
    float zy = act ? fmaf(dv, ay, bias[2 * fl + 1]) : -INFINITY;
    float m = fmaxf(zx, zy);
#pragma unroll
    for (int d = 16; d > 0; d >>= 1) m = fmaxf(m, __shfl_xor(m, d, 64));
    float ex = act ? (expf(zx - m) + expf(zy - m)) : 0.f;
#pragma unroll
    for (int d = 16; d > 0; d >>= 1) ex += __shfl_xor(ex, d, 64);
    float lse = m + logf(ex);
    if (h == 0 && act) {
        float2 o; o.x = zx - lse; o.y = zy - lse;
        *(float2*)&out[node * N_CLASSES + 2 * fl] = o;
    }
}

// ---------------- launch ----------------

extern "C" void kernel_launch(void* const* d_in, const int* in_sizes, int n_in,
                              void* d_out, int out_size, void* d_ws, size_t ws_size,
                              hipStream_t stream) {
    const float* x  = (const float*)d_in[0];
    const int*   ei = (const int*)d_in[1];
    const float* W1 = (const float*)d_in[2];
    const float* b1 = (const float*)d_in[3];
    const float* W2 = (const float*)d_in[4];
    const float* b2 = (const float*)d_in[5];
    const int* row = ei;             // edge_index[0] = source
    const int* col = ei + N_EDGES;   // edge_index[1] = target

    char* ws = (char*)d_ws;
    int*            btot   = (int*)(ws + 0);             // 628 B
    int*            gcur   = (int*)(ws + 1024);          // 628 B
    int*            off    = (int*)(ws + 4096);          // 160 KB + 4
    float*          dinv   = (float*)(ws + 167936);      // 160 KB
    unsigned*       sedge  = (unsigned*)(ws + 335872);   // 5.12 MB
    unsigned short* sorted = (unsigned short*)(ws + 5455872); // 2.56 MB
    _Float16*       W1t    = (_Float16*)(ws + 8015872);  // 128 KB
    _Float16*       B1     = (_Float16*)(ws + 8146944);  // 5.12 MB : hs1 f16
    _Float16*       B3     = (_Float16*)(ws + 13266944); // 3.2 MB : hs2 f16

    hipMemsetAsync(btot, 0, 2048, stream);   // btot + gcur
    k_pre<<<HIST_BLOCKS + CONV_BLOCKS, 256, 0, stream>>>(col, btot, W1, W1t);
    k_binscatter<<<(N_EDGES + CHUNK - 1) / CHUNK, 256, 0, stream>>>(row, col, btot, gcur, sedge);
    k_bucketsort<<<NB, 256, 0, stream>>>(sedge, btot, off, dinv, sorted);

    k_gemm1<<<N_NODES / 32, 256, 0, stream>>>(x, W1t, dinv, B1);
    k_g1g2<<<N_NODES / 4, 256, 0, stream>>>(off, sorted, B1, dinv, b1, W2, B3);
    k_gather2_lsm<<<(N_NODES + 3) / 4, 256, 0, stream>>>(off, sorted, B3, dinv, b2, (float*)d_out);
}